// Round 8
// baseline (53.958 us; speedup 1.0000x reference)
//
#include <hip/hip_runtime.h>
#include <hip/hip_cooperative_groups.h>
#include <math.h>

namespace cg = cooperative_groups;

#define B_   8
#define C_   4
#define H_   96
#define W_   96
#define HW_  9216
#define NBINS 18052              // exact d2 values 0..18050, plus bin 18051 == +inf
#define INFBIN 18051
#define NH32 ((NBINS + 1) / 2)   // 9026 packed words, 2 x u16 counters each
#define NT   1024                // threads per block (16 waves)
#define NBLK 64                  // B*C*2

// One block per (b, c, dir). dir==0: fwd (query = pred set, target = label set)
//                            dir==1: rev (query = label set, target = pred set)
// Cooperative grid: grid.sync() then block 0 finalizes (no counter, no memset).
__global__ __launch_bounds__(NT) void hd_main(const float* __restrict__ preds,
                                              const int*   __restrict__ labels,
                                              float* __restrict__ frws,
                                              float* __restrict__ out)
{
    __shared__ unsigned long long qmask[HW_ / 64];   // 1152 B query mask bits
    __shared__ unsigned long long tmask[HW_ / 64];   // 1152 B target mask bits
    __shared__ unsigned short g2u[HW_];              // 18432 B per-row 1D dist^2 (u16)
    __shared__ unsigned int   h32[NH32];             // 36104 B packed 16-bit histogram
    __shared__ int wsum[16];                         // 64 B wave-scan sums
    __shared__ int sc[6];                            // nT, nQ, n0, svlo, svhi, maxd2
    __shared__ float fr[NBLK];                       // finalize staging (block 0)

    cg::grid_group grid = cg::this_grid();

    const int id  = blockIdx.x;       // 0..63
    const int dir = id & 1;
    const int bc  = id >> 1;
    const int b   = bc >> 2;
    const int c   = bc & 3;
    const int tid = threadIdx.x;
    const int lane = tid & 63;
    const int wid  = tid >> 6;        // 0..15

    const float* Pb = preds  + (size_t)b * C_ * HW_;
    const int*   Lb = labels + (size_t)b * HW_;

    for (int i = tid; i < NH32; i += NT) h32[i] = 0u;
    if (tid == 0) { sc[0] = 0; sc[1] = 0; sc[2] = 0; sc[3] = -1; sc[4] = -1; sc[5] = 0; }
    __syncthreads();

    // ---- Step 1: fused argmax + both masks (+ counts, + |q ∩ t| = d2==0 count) ----
    {
        int myT = 0, myQ = 0, myN0 = 0;
        #pragma unroll 3
        for (int k = 0; k < HW_ / NT; ++k) {
            const int p = k * NT + tid;
            float v0 = Pb[p];
            float v1 = Pb[HW_ + p];
            float v2 = Pb[2 * HW_ + p];
            float v3 = Pb[3 * HW_ + p];
            int bi = 0; float bv = v0;
            if (v1 > bv) { bv = v1; bi = 1; }   // strict '>' keeps first max (jnp.argmax)
            if (v2 > bv) { bv = v2; bi = 2; }
            if (v3 > bv) { bv = v3; bi = 3; }
            const int lab = Lb[p];
            const bool pm = (bi == c);          // predicted-class mask
            const bool lm = (lab == c);         // label-class mask
            const bool qm = dir ? lm : pm;
            const bool tm = dir ? pm : lm;
            const unsigned long long qb = __ballot(qm);
            const unsigned long long tb = __ballot(tm);
            if (lane == 0) {
                qmask[p >> 6] = qb;
                tmask[p >> 6] = tb;
                myQ  += __popcll(qb);
                myT  += __popcll(tb);
                myN0 += __popcll(qb & tb);      // query pixels with d2 == 0
            }
        }
        if (lane == 0) {
            if (myT)  atomicAdd(&sc[0], myT);
            if (myQ)  atomicAdd(&sc[1], myQ);
            if (myN0) atomicAdd(&sc[2], myN0);
        }
    }
    __syncthreads();

    const int tEmpty = (sc[0] == 0);

    // ---- Step 2: horizontal nearest-set-bit distance via clz/ctz, per pixel ----
    // Row y = 96 bits: A = pixels x=0..63, Bw = pixels x=64..95 (low 32 bits).
    for (int k = 0; k < HW_ / NT; ++k) {
        const int p = k * NT + tid;
        const int y = p / W_;
        const int x = p - y * W_;
        const int bp = y * W_;                 // row start bit position
        const int wi = bp >> 6;
        const int sh = bp & 63;                // 0 (even y) or 32 (odd y)
        const unsigned long long w0 = tmask[wi];
        const unsigned long long w1 = tmask[wi + 1];
        unsigned long long A, Bw;
        if (sh == 0) { A = w0;                       Bw = w1 & 0xFFFFFFFFull; }
        else         { A = (w0 >> 32) | (w1 << 32); Bw = w1 >> 32; }

        int dl = 1000, dr = 1000;
        if (x < 64) {
            const unsigned long long ml = A & ((2ull << x) - 1ull);   // bits <= x (x=63 wraps to ~0)
            if (ml) dl = x - (63 - __builtin_clzll(ml));
            const unsigned long long mr = A & ~((1ull << x) - 1ull);  // bits >= x
            if (mr)      dr = __builtin_ctzll(mr) - x;
            else if (Bw) dr = 64 + __builtin_ctzll(Bw) - x;
        } else {
            const int xb = x - 64;                                    // 0..31
            const unsigned long long ml = Bw & ((2ull << xb) - 1ull);
            if (ml)     dl = x - (64 + 63 - __builtin_clzll(ml));
            else if (A) dl = x - (63 - __builtin_clzll(A));
            const unsigned long long mr = Bw & ~((1ull << xb) - 1ull);
            if (mr) dr = 64 + __builtin_ctzll(mr) - x;
        }
        const int g = min(dl, dr);
        g2u[p] = (g >= 96) ? (unsigned short)40000     // row empty: > any real d2
                           : (unsigned short)(g * g);
    }
    __syncthreads();

    // ---- Step 3: exact outward early-exit column scan, query pixels only ----
    // d2(y,x) = min_r (y-r)^2 + g2(r,x). Scanning off = |y-r| outward, once
    // off^2 >= best no farther row can improve (g2 >= 0) -> exact early exit.
    // Also tracks maxd2 so step 4 only scans live bins.
    if (!tEmpty) {
        int bmax = 0;
        for (int k = 0; k < HW_ / NT; ++k) {
            const int p = k * NT + tid;
            const int qbit = (int)((qmask[p >> 6] >> (p & 63)) & 1ull);
            if (!qbit) continue;
            const int tbit = (int)((tmask[p >> 6] >> (p & 63)) & 1ull);
            if (tbit) continue;                          // d2 == 0, counted via popcount
            const int y = p / W_;
            const int x = p - y * W_;
            int best = (int)g2u[p];                      // off = 0 row
            for (int off = 1; off < H_; ++off) {
                const int o2 = off * off;
                if (o2 >= best) break;
                const int r1 = y - off;
                const int r2 = y + off;
                if (r1 >= 0) best = min(best, o2 + (int)g2u[r1 * W_ + x]);
                if (r2 < H_) best = min(best, o2 + (int)g2u[r2 * W_ + x]);
            }
            bmax = max(bmax, best);
            atomicAdd(&h32[best >> 1], 1u << ((best & 1) << 4));  // best in [1, 18050]
        }
        #pragma unroll
        for (int d = 32; d >= 1; d >>= 1) bmax = max(bmax, __shfl_xor(bmax, d, 64));
        if (lane == 0 && bmax > 0) atomicMax(&sc[5], bmax);
    }
    __syncthreads();

    // ---- Step 4: exact rank selection, parallel prefix scan over live bins ----
    // Bin 0's count (= |q ∩ t|, popcount) folded in at the thread owning bin 0.
    // Bins > maxd2 are provably zero (nothing histogrammed above it; INFBIN unused
    // -> empty-target leaves svlo/svhi = -1 -> inf -> literal formula matches ref).
    const int n = sc[1];
    const int maxd2 = sc[5];
    const int h0x = (!tEmpty) ? sc[2] : 0;
    const int CHUNK = (NBINS + NT - 1) / NT;             // 18
    const int base_i = tid * CHUNK;
    int lsum = (base_i == 0) ? h0x : 0;
    for (int j = 0; j < CHUNK; ++j) {
        const int i = base_i + j;
        if (i > maxd2) break;
        lsum += (int)((h32[i >> 1] >> ((i & 1) << 4)) & 0xFFFFu);
    }
    // wave-level inclusive scan of lsum
    int incl = lsum;
    #pragma unroll
    for (int d = 1; d < 64; d <<= 1) {
        const int t = __shfl_up(incl, d, 64);
        if (lane >= d) incl += t;
    }
    if (lane == 63) wsum[wid] = incl;
    __syncthreads();
    if (wid == 0) {                                      // scan the 16 wave sums
        const int w = (lane < 16) ? wsum[lane] : 0;
        int wincl = w;
        #pragma unroll
        for (int d = 1; d < 16; d <<= 1) {
            const int t = __shfl_up(wincl, d, 64);
            if (lane >= d) wincl += t;
        }
        if (lane < 16) wsum[lane] = wincl - w;           // exclusive wave prefix
    }
    __syncthreads();

    int nm1 = n - 1; if (nm1 < 0) nm1 = 0;
    const float posf = 0.95f * (float)nm1;               // matches (q/100)*f32(n-1)
    const int lo = (int)floorf(posf);
    const int hi = (int)ceilf(posf);
    const float frac = posf - (float)lo;

    int run = (incl - lsum) + wsum[wid];                 // exclusive prefix over bins < base_i
    for (int j = 0; j < CHUNK; ++j) {
        const int i = base_i + j;
        if (i > maxd2) break;
        int h = (int)((h32[i >> 1] >> ((i & 1) << 4)) & 0xFFFFu);
        if (i == 0) h += h0x;
        if (h > 0) {
            const int nrun = run + h;
            if (run <= lo && lo < nrun) sc[3] = i;       // exactly one thread hits each
            if (run <= hi && hi < nrun) sc[4] = i;
            run = nrun;
        }
    }
    __syncthreads();

    // ---- Publish per-(b,c,dir) result, grid-wide sync, block 0 finalizes ----
    if (tid == 0) {
        const int svlo = sc[3], svhi = sc[4];
        const float vlo = (svlo < 0 || svlo == INFBIN) ? __builtin_inff()
                                                       : (float)sqrt((double)svlo);
        const float vhi = (svhi < 0 || svhi == INFBIN) ? __builtin_inff()
                                                       : (float)sqrt((double)svhi);
        // literal reference arithmetic (inf*0 -> nan semantics preserved)
        const float v = vlo * (1.0f - frac) + vhi * frac;
        __hip_atomic_store(&frws[id], v, __ATOMIC_RELEASE, __HIP_MEMORY_SCOPE_AGENT);
    }

    grid.sync();

    if (id != 0) return;
    if (wid == 0) {
        fr[lane] = __hip_atomic_load(&frws[lane], __ATOMIC_ACQUIRE,
                                     __HIP_MEMORY_SCOPE_AGENT);
    }
    __syncthreads();
    if (tid == 0) {
        float F[4], R[4], M[4];
        for (int cc = 0; cc < 4; ++cc) {
            if (cc == 0) { F[cc] = R[cc] = M[cc] = 0.0f; continue; }  // IGNORE class
            float sf = 0.0f, sr = 0.0f, sm = 0.0f;
            for (int bb = 0; bb < 8; ++bb) {
                const float f = fr[((bb * 4 + cc) << 1) + 0];
                const float r = fr[((bb * 4 + cc) << 1) + 1];
                sf += f; sr += r;
                float m = f > r ? f : r;
                if (f != f || r != r) m = f + r;        // NaN-propagating maximum
                sm += m;
            }
            F[cc] = sf / 8.0f; R[cc] = sr / 8.0f; M[cc] = sm / 8.0f;
        }
        // out = concat(MHD, FHD, RHD), each [c0..c3, mean(all), mean(excl c0)]
        float* o = out;
        o[0] = M[0]; o[1] = M[1]; o[2] = M[2]; o[3] = M[3];
        o[4] = (M[0] + M[1] + M[2] + M[3]) / 4.0f;
        o[5] = (M[1] + M[2] + M[3]) / 3.0f;
        o += 6;
        o[0] = F[0]; o[1] = F[1]; o[2] = F[2]; o[3] = F[3];
        o[4] = (F[0] + F[1] + F[2] + F[3]) / 4.0f;
        o[5] = (F[1] + F[2] + F[3]) / 3.0f;
        o += 6;
        o[0] = R[0]; o[1] = R[1]; o[2] = R[2]; o[3] = R[3];
        o[4] = (R[0] + R[1] + R[2] + R[3]) / 4.0f;
        o[5] = (R[1] + R[2] + R[3]) / 3.0f;
    }
}

extern "C" void kernel_launch(void* const* d_in, const int* in_sizes, int n_in,
                              void* d_out, int out_size, void* d_ws, size_t ws_size,
                              hipStream_t stream)
{
    const float* preds  = (const float*)d_in[0];
    const int*   labels = (const int*)d_in[1];
    float*       frws   = (float*)d_ws;          // 64 floats staging (f,r per b,c)
    float*       out    = (float*)d_out;

    void* args[] = { (void*)&preds, (void*)&labels, (void*)&frws, (void*)&out };
    hipLaunchCooperativeKernel((const void*)hd_main, dim3(NBLK), dim3(NT),
                               args, 0, stream);
}

// Round 9
// 24.132 us; speedup vs baseline: 2.2360x; 2.2360x over previous
//
#include <hip/hip_runtime.h>
#include <math.h>

#define B_   8
#define C_   4
#define H_   96
#define W_   96
#define HW_  9216
#define NBINS 18052              // exact d2 values 0..18050 (+inf case handled via svlo=-1)
#define INFBIN 18051
#define NH32 ((NBINS + 1) / 2)   // 9026 packed words, 2 x u16 counters each
#define NT   1024                // threads per block (16 waves)
#define NBLK 64                  // B*C*2
#define NW   16                  // waves per block

// One block per (b, c, dir). dir==0: fwd (query = pred set, target = label set)
//                            dir==1: rev (query = label set, target = pred set)
__global__ __launch_bounds__(NT) void hd_main(const float* __restrict__ preds,
                                              const int*   __restrict__ labels,
                                              float* __restrict__ frws)
{
    __shared__ unsigned long long qmask[HW_ / 64];   // 1152 B query mask bits
    __shared__ unsigned long long tmask[HW_ / 64];   // 1152 B target mask bits
    __shared__ unsigned short g2u[HW_];              // 18432 B per-row 1D dist^2 (u16)
    __shared__ unsigned int   h32[NH32];             // 36104 B packed 16-bit histogram
    __shared__ int wsum[NW];                         // scan partials
    __shared__ int twv[NW], qwv[NW], zwv[NW], bwv[NW]; // per-wave nT, nQ, n0, bmax
    __shared__ int svsel[2];                         // svlo, svhi

    const int id  = blockIdx.x;       // 0..63
    const int dir = id & 1;
    const int bc  = id >> 1;
    const int b   = bc >> 2;
    const int c   = bc & 3;
    const int tid = threadIdx.x;
    const int lane = tid & 63;
    const int wid  = tid >> 6;        // 0..15

    const float* Pb = preds  + (size_t)b * C_ * HW_;
    const int*   Lb = labels + (size_t)b * HW_;

    // hist clear (used first in step 3, after barrier 2) — no extra barrier needed
    for (int i = tid; i < NH32; i += NT) h32[i] = 0u;
    if (tid == 0) { svsel[0] = -1; svsel[1] = -1; }

    // ---- Step 1: fused argmax + both masks; per-wave counts (no atomics) ----
    {
        int myT = 0, myQ = 0, myN0 = 0;
        #pragma unroll 3
        for (int k = 0; k < HW_ / NT; ++k) {
            const int p = k * NT + tid;
            float v0 = Pb[p];
            float v1 = Pb[HW_ + p];
            float v2 = Pb[2 * HW_ + p];
            float v3 = Pb[3 * HW_ + p];
            int bi = 0; float bv = v0;
            if (v1 > bv) { bv = v1; bi = 1; }   // strict '>' keeps first max (jnp.argmax)
            if (v2 > bv) { bv = v2; bi = 2; }
            if (v3 > bv) { bv = v3; bi = 3; }
            const int lab = Lb[p];
            const bool pm = (bi == c);          // predicted-class mask
            const bool lm = (lab == c);         // label-class mask
            const bool qm = dir ? lm : pm;
            const bool tm = dir ? pm : lm;
            const unsigned long long qb = __ballot(qm);
            const unsigned long long tb = __ballot(tm);
            if (lane == 0) {
                qmask[p >> 6] = qb;
                tmask[p >> 6] = tb;
                myQ  += __popcll(qb);
                myT  += __popcll(tb);
                myN0 += __popcll(qb & tb);      // query pixels with d2 == 0
            }
        }
        if (lane == 0) { twv[wid] = myT; qwv[wid] = myQ; zwv[wid] = myN0; }
    }
    __syncthreads();                                     // barrier 1

    int nT = 0;
    #pragma unroll
    for (int w = 0; w < NW; ++w) nT += twv[w];           // broadcast LDS reads
    const int tEmpty = (nT == 0);

    // ---- Step 2: horizontal nearest-set-bit distance via clz/ctz, per pixel ----
    // Row y = 96 bits: A = pixels x=0..63, Bw = pixels x=64..95 (low 32 bits).
    for (int k = 0; k < HW_ / NT; ++k) {
        const int p = k * NT + tid;
        const int y = p / W_;
        const int x = p - y * W_;
        const int bp = y * W_;                 // row start bit position
        const int wi = bp >> 6;
        const int sh = bp & 63;                // 0 (even y) or 32 (odd y)
        const unsigned long long w0 = tmask[wi];
        const unsigned long long w1 = tmask[wi + 1];
        unsigned long long A, Bw;
        if (sh == 0) { A = w0;                       Bw = w1 & 0xFFFFFFFFull; }
        else         { A = (w0 >> 32) | (w1 << 32); Bw = w1 >> 32; }

        int dl = 1000, dr = 1000;
        if (x < 64) {
            const unsigned long long ml = A & ((2ull << x) - 1ull);   // bits <= x (x=63 wraps to ~0)
            if (ml) dl = x - (63 - __builtin_clzll(ml));
            const unsigned long long mr = A & ~((1ull << x) - 1ull);  // bits >= x
            if (mr)      dr = __builtin_ctzll(mr) - x;
            else if (Bw) dr = 64 + __builtin_ctzll(Bw) - x;
        } else {
            const int xb = x - 64;                                    // 0..31
            const unsigned long long ml = Bw & ((2ull << xb) - 1ull);
            if (ml)     dl = x - (64 + 63 - __builtin_clzll(ml));
            else if (A) dl = x - (63 - __builtin_clzll(A));
            const unsigned long long mr = Bw & ~((1ull << xb) - 1ull);
            if (mr) dr = 64 + __builtin_ctzll(mr) - x;
        }
        const int g = min(dl, dr);
        g2u[p] = (g >= 96) ? (unsigned short)40000     // row empty: > any real d2
                           : (unsigned short)(g * g);
    }
    __syncthreads();                                     // barrier 2

    // ---- Step 3: exact column scan — speculative window (off 0..2 unconditional,
    // independent reads) + rare dependent tail. Tracks per-wave max d2. ----
    {
        int bmax = 0;
        if (!tEmpty) {
            for (int k = 0; k < HW_ / NT; ++k) {
                const int p = k * NT + tid;
                const int qbit = (int)((qmask[p >> 6] >> (p & 63)) & 1ull);
                if (!qbit) continue;
                const int tbit = (int)((tmask[p >> 6] >> (p & 63)) & 1ull);
                if (tbit) continue;                      // d2 == 0, counted via popcount
                const int y = p / W_;
                const int x = p - y * W_;
                // unconditional window: rows y, y±1, y±2 (5 independent LDS reads)
                const int a0 = (int)g2u[p];
                const int a1 = (y >= 1)      ? (int)g2u[p - W_]     : 0x7FFF0000;
                const int a2 = (y + 1 < H_)  ? (int)g2u[p + W_]     : 0x7FFF0000;
                const int a3 = (y >= 2)      ? (int)g2u[p - 2 * W_] : 0x7FFF0000;
                const int a4 = (y + 2 < H_)  ? (int)g2u[p + 2 * W_] : 0x7FFF0000;
                int best = min(a0, min(min(a1 + 1, a2 + 1), min(a3 + 4, a4 + 4)));
                // exact tail: prune is exact (candidates at off' >= off are >= o2 >= best)
                for (int off = 3; off < H_; ++off) {
                    const int o2 = off * off;
                    if (o2 >= best) break;
                    const int r1 = y - off;
                    const int r2 = y + off;
                    if (r1 >= 0) best = min(best, o2 + (int)g2u[r1 * W_ + x]);
                    if (r2 < H_) best = min(best, o2 + (int)g2u[r2 * W_ + x]);
                }
                bmax = max(bmax, best);
                atomicAdd(&h32[best >> 1], 1u << ((best & 1) << 4));  // best in [1,18050]
            }
        }
        #pragma unroll
        for (int d = 32; d >= 1; d >>= 1) bmax = max(bmax, __shfl_xor(bmax, d, 64));
        if (lane == 0) bwv[wid] = bmax;                  // defined even when tEmpty
    }
    __syncthreads();                                     // barrier 3

    // ---- Step 4: exact rank selection over live bins only (<= maxd2) ----
    int nQ = 0, n0 = 0, maxd2 = 0;
    #pragma unroll
    for (int w = 0; w < NW; ++w) {
        nQ += qwv[w]; n0 += zwv[w]; maxd2 = max(maxd2, bwv[w]);
    }
    const int h0x = (!tEmpty) ? n0 : 0;                  // bin 0 count via popcount
    const int CHUNK = (NBINS + NT - 1) / NT;             // 18
    const int base_i = tid * CHUNK;
    int lsum = (base_i == 0) ? h0x : 0;
    for (int j = 0; j < CHUNK; ++j) {
        const int i = base_i + j;
        if (i > maxd2) break;
        lsum += (int)((h32[i >> 1] >> ((i & 1) << 4)) & 0xFFFFu);
    }
    // wave-level inclusive scan of lsum
    int incl = lsum;
    #pragma unroll
    for (int d = 1; d < 64; d <<= 1) {
        const int t = __shfl_up(incl, d, 64);
        if (lane >= d) incl += t;
    }
    if (lane == 63) wsum[wid] = incl;
    __syncthreads();                                     // barrier 4
    if (wid == 0) {                                      // scan the 16 wave sums
        const int w = (lane < NW) ? wsum[lane] : 0;
        int wincl = w;
        #pragma unroll
        for (int d = 1; d < NW; d <<= 1) {
            const int t = __shfl_up(wincl, d, 64);
            if (lane >= d) wincl += t;
        }
        if (lane < NW) wsum[lane] = wincl - w;           // exclusive wave prefix
    }
    __syncthreads();                                     // barrier 5

    int nm1 = nQ - 1; if (nm1 < 0) nm1 = 0;
    const float posf = 0.95f * (float)nm1;               // matches (q/100)*f32(n-1)
    const int lo = (int)floorf(posf);
    const int hi = (int)ceilf(posf);
    const float frac = posf - (float)lo;

    int run = (incl - lsum) + wsum[wid];                 // exclusive prefix over bins < base_i
    for (int j = 0; j < CHUNK; ++j) {
        const int i = base_i + j;
        if (i > maxd2) break;
        int h = (int)((h32[i >> 1] >> ((i & 1) << 4)) & 0xFFFFu);
        if (i == 0) h += h0x;
        if (h > 0) {
            const int nrun = run + h;
            if (run <= lo && lo < nrun) svsel[0] = i;    // exactly one thread hits each
            if (run <= hi && hi < nrun) svsel[1] = i;
            run = nrun;
        }
    }
    __syncthreads();                                     // barrier 6

    if (tid == 0) {
        const int svlo = svsel[0], svhi = svsel[1];
        // tEmpty (or nQ==0) leaves sv = -1 -> inf; literal reference arithmetic
        // (inf*0 -> nan semantics preserved)
        const float vlo = (svlo < 0) ? __builtin_inff() : (float)sqrt((double)svlo);
        const float vhi = (svhi < 0) ? __builtin_inff() : (float)sqrt((double)svhi);
        frws[id] = vlo * (1.0f - frac) + vhi * frac;
    }
}

__global__ __launch_bounds__(64) void hd_fin(const float* __restrict__ frws,
                                             float* __restrict__ out)
{
    __shared__ float fr[NBLK];
    const int tid = threadIdx.x;
    fr[tid] = frws[tid];                                 // parallel load (64 values)
    __syncthreads();
    if (tid == 0) {
        float F[4], R[4], M[4];
        for (int c = 0; c < 4; ++c) {
            if (c == 0) { F[c] = R[c] = M[c] = 0.0f; continue; }  // IGNORE class
            float sf = 0.0f, sr = 0.0f, sm = 0.0f;
            for (int b = 0; b < 8; ++b) {
                const float f = fr[((b * 4 + c) << 1) + 0];
                const float r = fr[((b * 4 + c) << 1) + 1];
                sf += f; sr += r;
                float m = f > r ? f : r;
                if (f != f || r != r) m = f + r;        // NaN-propagating maximum
                sm += m;
            }
            F[c] = sf / 8.0f; R[c] = sr / 8.0f; M[c] = sm / 8.0f;
        }
        // out = concat(MHD, FHD, RHD), each [c0..c3, mean(all), mean(excl c0)]
        float* o = out;
        o[0] = M[0]; o[1] = M[1]; o[2] = M[2]; o[3] = M[3];
        o[4] = (M[0] + M[1] + M[2] + M[3]) / 4.0f;
        o[5] = (M[1] + M[2] + M[3]) / 3.0f;
        o += 6;
        o[0] = F[0]; o[1] = F[1]; o[2] = F[2]; o[3] = F[3];
        o[4] = (F[0] + F[1] + F[2] + F[3]) / 4.0f;
        o[5] = (F[1] + F[2] + F[3]) / 3.0f;
        o += 6;
        o[0] = R[0]; o[1] = R[1]; o[2] = R[2]; o[3] = R[3];
        o[4] = (R[0] + R[1] + R[2] + R[3]) / 4.0f;
        o[5] = (R[1] + R[2] + R[3]) / 3.0f;
    }
}

extern "C" void kernel_launch(void* const* d_in, const int* in_sizes, int n_in,
                              void* d_out, int out_size, void* d_ws, size_t ws_size,
                              hipStream_t stream)
{
    const float* preds  = (const float*)d_in[0];
    const int*   labels = (const int*)d_in[1];
    float* frws = (float*)d_ws;                  // 64 floats staging (f,r per b,c)

    hipLaunchKernelGGL(hd_main, dim3(NBLK), dim3(NT), 0, stream,
                       preds, labels, frws);
    hipLaunchKernelGGL(hd_fin, dim3(1), dim3(64), 0, stream,
                       frws, (float*)d_out);
}

// Round 10
// 20.466 us; speedup vs baseline: 2.6365x; 1.1791x over previous
//
#include <hip/hip_runtime.h>
#include <math.h>

#define B_   8
#define C_   4
#define H_   96
#define W_   96
#define HW_  9216
#define NBINS 18052              // exact d2 values 0..18050 (+inf case via svlo=-1)
#define NH32 ((NBINS + 1) / 2)   // 9026 packed words, 2 x u16 counters each
#define NT   1024                // threads per block (16 waves)
#define NBLK 64                  // B*C*2
#define NW   16                  // waves per block
#define NGRP 1152                // 8-pixel groups (HW/8)

// One block per (b, c, dir). dir==0: fwd (query = pred set, target = label set)
//                            dir==1: rev (query = label set, target = pred set)
__global__ __launch_bounds__(NT) void hd_main(const float* __restrict__ preds,
                                              const int*   __restrict__ labels,
                                              float* __restrict__ frws)
{
    __shared__ unsigned char  qmb[NGRP];             // query mask bits (bit j of byte g = px 8g+j)
    __shared__ unsigned char  tmb[NGRP];             // target mask bits
    __shared__ unsigned short g2u[HW_];              // per-row 1D dist^2 (u16)
    __shared__ unsigned int   h32[NH32];             // packed 16-bit histogram
    __shared__ int twv[NW], qwv[NW], zwv[NW], bwv[NW]; // per-wave nT, nQ, n0, bmax

    const int id  = blockIdx.x;       // 0..63
    const int dir = id & 1;
    const int bc  = id >> 1;
    const int b   = bc >> 2;
    const int c   = bc & 3;
    const int tid = threadIdx.x;
    const int lane = tid & 63;
    const int wid  = tid >> 6;        // 0..15

    const float* Pb = preds  + (size_t)b * C_ * HW_;
    const int*   Lb = labels + (size_t)b * HW_;

    // hist clear (first used in step 3, after barrier 2)
    for (int i = tid; i < NH32; i += NT) h32[i] = 0u;

    // ---- Step 1: vectorized argmax + masks (8 px/group), per-wave counts ----
    {
        int myT = 0, myQ = 0, myN0 = 0;
        #pragma unroll
        for (int k = 0; k < 2; ++k) {
            const int g = k * NT + tid;
            if (g < NGRP) {
                const int bp = g * 8;
                const float4 a0 = *(const float4*)(Pb + bp);
                const float4 b0 = *(const float4*)(Pb + bp + 4);
                const float4 a1 = *(const float4*)(Pb + HW_ + bp);
                const float4 b1 = *(const float4*)(Pb + HW_ + bp + 4);
                const float4 a2 = *(const float4*)(Pb + 2 * HW_ + bp);
                const float4 b2 = *(const float4*)(Pb + 2 * HW_ + bp + 4);
                const float4 a3 = *(const float4*)(Pb + 3 * HW_ + bp);
                const float4 b3 = *(const float4*)(Pb + 3 * HW_ + bp + 4);
                const int4   l0 = *(const int4*)(Lb + bp);
                const int4   l1 = *(const int4*)(Lb + bp + 4);
                unsigned tb = 0, qb = 0;
                // strict '>' keeps first max (jnp.argmax semantics)
                #define PX_(j, e0, e1, e2, e3, lj)                              \
                {   int bi = 0; float bv = (e0);                                \
                    if ((e1) > bv) { bv = (e1); bi = 1; }                       \
                    if ((e2) > bv) { bv = (e2); bi = 2; }                       \
                    if ((e3) > bv) { bv = (e3); bi = 3; }                       \
                    const bool pm = (bi == c);                                  \
                    const bool lm = ((lj) == c);                                \
                    const bool qm = dir ? lm : pm;                              \
                    const bool tm = dir ? pm : lm;                              \
                    tb |= (unsigned)tm << (j); qb |= (unsigned)qm << (j); }
                PX_(0, a0.x, a1.x, a2.x, a3.x, l0.x)
                PX_(1, a0.y, a1.y, a2.y, a3.y, l0.y)
                PX_(2, a0.z, a1.z, a2.z, a3.z, l0.z)
                PX_(3, a0.w, a1.w, a2.w, a3.w, l0.w)
                PX_(4, b0.x, b1.x, b2.x, b3.x, l1.x)
                PX_(5, b0.y, b1.y, b2.y, b3.y, l1.y)
                PX_(6, b0.z, b1.z, b2.z, b3.z, l1.z)
                PX_(7, b0.w, b1.w, b2.w, b3.w, l1.w)
                #undef PX_
                tmb[g] = (unsigned char)tb;
                qmb[g] = (unsigned char)qb;
                myT  += __popc(tb);
                myQ  += __popc(qb);
                myN0 += __popc(tb & qb);     // query px with d2 == 0
            }
        }
        #pragma unroll
        for (int d = 32; d >= 1; d >>= 1) {
            myT  += __shfl_xor(myT,  d, 64);
            myQ  += __shfl_xor(myQ,  d, 64);
            myN0 += __shfl_xor(myN0, d, 64);
        }
        if (lane == 0) { twv[wid] = myT; qwv[wid] = myQ; zwv[wid] = myN0; }
    }
    __syncthreads();                                     // barrier 1

    int nT = 0;
    #pragma unroll
    for (int w = 0; w < NW; ++w) nT += twv[w];           // broadcast LDS reads
    const int tEmpty = (nT == 0);

    // ---- Step 2: horizontal nearest-set-bit distance via clz/ctz ----
    // Row y = bytes tmb[12y..12y+11]; A = px 0..63, Bw = px 64..95.
    for (int k = 0; k < HW_ / NT; ++k) {
        const int p = k * NT + tid;
        const int y = p / W_;
        const int x = p - y * W_;
        const unsigned r0 = *(const unsigned*)(tmb + 12 * y);
        const unsigned r1 = *(const unsigned*)(tmb + 12 * y + 4);
        const unsigned r2 = *(const unsigned*)(tmb + 12 * y + 8);
        const unsigned long long A  = (unsigned long long)r0 |
                                      ((unsigned long long)r1 << 32);
        const unsigned long long Bw = r2;

        int dl = 1000, dr = 1000;
        if (x < 64) {
            const unsigned long long ml = A & ((2ull << x) - 1ull);   // bits <= x
            if (ml) dl = x - (63 - __builtin_clzll(ml));
            const unsigned long long mr = A & ~((1ull << x) - 1ull);  // bits >= x
            if (mr)      dr = __builtin_ctzll(mr) - x;
            else if (Bw) dr = 64 + __builtin_ctzll(Bw) - x;
        } else {
            const int xb = x - 64;                                    // 0..31
            const unsigned long long ml = Bw & ((2ull << xb) - 1ull);
            if (ml)     dl = x - (64 + 63 - __builtin_clzll(ml));
            else if (A) dl = x - (63 - __builtin_clzll(A));
            const unsigned long long mr = Bw & ~((1ull << xb) - 1ull);
            if (mr) dr = 64 + __builtin_ctzll(mr) - x;
        }
        const int g = min(dl, dr);
        g2u[p] = (g >= 96) ? (unsigned short)40000     // row empty: > any real d2
                           : (unsigned short)(g * g);
    }
    __syncthreads();                                     // barrier 2

    // ---- Step 3: exact column scan — speculative ±2 window + rare tail ----
    {
        int bmax = 0;
        if (!tEmpty) {
            for (int k = 0; k < HW_ / NT; ++k) {
                const int p = k * NT + tid;
                const int byi = p >> 3, bsh = p & 7;
                if (!((qmb[byi] >> bsh) & 1)) continue;
                if ((tmb[byi] >> bsh) & 1) continue;     // d2 == 0, via popcount
                const int y = p / W_;
                const int x = p - y * W_;
                const int a0 = (int)g2u[p];
                const int a1 = (y >= 1)     ? (int)g2u[p - W_]     : 0x7FFF0000;
                const int a2 = (y + 1 < H_) ? (int)g2u[p + W_]     : 0x7FFF0000;
                const int a3 = (y >= 2)     ? (int)g2u[p - 2 * W_] : 0x7FFF0000;
                const int a4 = (y + 2 < H_) ? (int)g2u[p + 2 * W_] : 0x7FFF0000;
                int best = min(a0, min(min(a1 + 1, a2 + 1), min(a3 + 4, a4 + 4)));
                for (int off = 3; off < H_; ++off) {     // exact prune
                    const int o2 = off * off;
                    if (o2 >= best) break;
                    const int r1 = y - off;
                    const int r2 = y + off;
                    if (r1 >= 0) best = min(best, o2 + (int)g2u[r1 * W_ + x]);
                    if (r2 < H_) best = min(best, o2 + (int)g2u[r2 * W_ + x]);
                }
                bmax = max(bmax, best);
                atomicAdd(&h32[best >> 1], 1u << ((best & 1) << 4));  // [1,18050]
            }
        }
        #pragma unroll
        for (int d = 32; d >= 1; d >>= 1) bmax = max(bmax, __shfl_xor(bmax, d, 64));
        if (lane == 0) bwv[wid] = bmax;
    }
    __syncthreads();                                     // barrier 3 (last)

    if (wid != 0) return;                                // waves 1..15 done

    // ---- Step 4: single-wave exact rank selection over live bins ----
    int nQ = 0, n0s = 0, maxd2 = 0;
    #pragma unroll
    for (int w = 0; w < NW; ++w) {
        nQ += qwv[w]; n0s += zwv[w]; maxd2 = max(maxd2, bwv[w]);
    }
    const int h0x = tEmpty ? 0 : n0s;                    // bin-0 count via popcount

    int nm1 = nQ - 1; if (nm1 < 0) nm1 = 0;
    const float posf = 0.95f * (float)nm1;               // matches (q/100)*f32(n-1)
    const int lo = (int)floorf(posf);
    const int hi = (int)ceilf(posf);
    const float frac = posf - (float)lo;

    int svlo = -1, svhi = -1;
    if (!tEmpty) {
        int run = 0;
        for (int base = 0; base <= maxd2; base += 64) {  // striped rounds of 64 bins
            const int i = base + lane;
            int h = 0;
            if (i <= maxd2) {
                h = (int)((h32[i >> 1] >> ((i & 1) << 4)) & 0xFFFFu);
                if (i == 0) h += h0x;
            }
            int inc = h;
            #pragma unroll
            for (int d = 1; d < 64; d <<= 1) {
                const int t = __shfl_up(inc, d, 64);
                if (lane >= d) inc += t;
            }
            const int excl = run + inc - h;              // exclusive prefix of bin i
            if (h > 0) {
                if (excl <= lo && lo < excl + h) svlo = i;
                if (excl <= hi && hi < excl + h) svhi = i;
            }
            run += __shfl(inc, 63, 64);                  // add round total
        }
        #pragma unroll
        for (int d = 32; d >= 1; d >>= 1) {              // exactly one lane found each
            svlo = max(svlo, __shfl_xor(svlo, d, 64));
            svhi = max(svhi, __shfl_xor(svhi, d, 64));
        }
    }
    if (lane == 0) {
        // sv<0 (empty target or empty query) -> inf; literal reference arithmetic
        // (inf*0 -> nan semantics preserved)
        const float vlo = (svlo < 0) ? __builtin_inff() : (float)sqrt((double)svlo);
        const float vhi = (svhi < 0) ? __builtin_inff() : (float)sqrt((double)svhi);
        frws[id] = vlo * (1.0f - frac) + vhi * frac;
    }
}

__global__ __launch_bounds__(64) void hd_fin(const float* __restrict__ frws,
                                             float* __restrict__ out)
{
    __shared__ float fr[NBLK];
    const int tid = threadIdx.x;
    fr[tid] = frws[tid];                                 // parallel load (64 values)
    __syncthreads();
    if (tid == 0) {
        float F[4], R[4], M[4];
        for (int c = 0; c < 4; ++c) {
            if (c == 0) { F[c] = R[c] = M[c] = 0.0f; continue; }  // IGNORE class
            float sf = 0.0f, sr = 0.0f, sm = 0.0f;
            for (int b = 0; b < 8; ++b) {
                const float f = fr[((b * 4 + c) << 1) + 0];
                const float r = fr[((b * 4 + c) << 1) + 1];
                sf += f; sr += r;
                float m = f > r ? f : r;
                if (f != f || r != r) m = f + r;        // NaN-propagating maximum
                sm += m;
            }
            F[c] = sf / 8.0f; R[c] = sr / 8.0f; M[c] = sm / 8.0f;
        }
        // out = concat(MHD, FHD, RHD), each [c0..c3, mean(all), mean(excl c0)]
        float* o = out;
        o[0] = M[0]; o[1] = M[1]; o[2] = M[2]; o[3] = M[3];
        o[4] = (M[0] + M[1] + M[2] + M[3]) / 4.0f;
        o[5] = (M[1] + M[2] + M[3]) / 3.0f;
        o += 6;
        o[0] = F[0]; o[1] = F[1]; o[2] = F[2]; o[3] = F[3];
        o[4] = (F[0] + F[1] + F[2] + F[3]) / 4.0f;
        o[5] = (F[1] + F[2] + F[3]) / 3.0f;
        o += 6;
        o[0] = R[0]; o[1] = R[1]; o[2] = R[2]; o[3] = R[3];
        o[4] = (R[0] + R[1] + R[2] + R[3]) / 4.0f;
        o[5] = (R[1] + R[2] + R[3]) / 3.0f;
    }
}

extern "C" void kernel_launch(void* const* d_in, const int* in_sizes, int n_in,
                              void* d_out, int out_size, void* d_ws, size_t ws_size,
                              hipStream_t stream)
{
    const float* preds  = (const float*)d_in[0];
    const int*   labels = (const int*)d_in[1];
    float* frws = (float*)d_ws;                  // 64 floats staging (f,r per b,c)

    hipLaunchKernelGGL(hd_main, dim3(NBLK), dim3(NT), 0, stream,
                       preds, labels, frws);
    hipLaunchKernelGGL(hd_fin, dim3(1), dim3(64), 0, stream,
                       frws, (float*)d_out);
}